// Round 1
// baseline (2393.716 us; speedup 1.0000x reference)
//
#include <hip/hip_runtime.h>

typedef unsigned short u16;

#define NWG 256
#define NT  256
#define TS  512
#define HD  1024
#define BS  128
#define NI  64
#define NO  64
#define GR  2       // out-of-phase row-groups per XCD (sync latency hides under other group's compute)
#define GXR 8       // batch rows per group (8 XCDs x 16 rows total, split 2x8)
#define CC  32      // hidden cols per CU
#define RCP 17      // redC padded row stride
#define MBW 32      // u32 words per consumer-group mailbox (128B = 2 lines)

typedef __attribute__((ext_vector_type(8))) short bf16x8;
typedef __attribute__((ext_vector_type(4))) float f32x4;

__device__ __forceinline__ float bf2f(u16 u) {
    union { unsigned int i; float f; } v; v.i = ((unsigned int)u) << 16; return v.f;
}
__device__ __forceinline__ u16 f2bf(float f) {
    union { float fl; unsigned int i; } v; v.fl = f;
    unsigned int x = v.i;
    return (u16)((x + 0x7fffu + ((x >> 16) & 1u)) >> 16);  // RNE, finite inputs
}
__device__ __forceinline__ float ldv(const void* p, size_t i, bool isf32) {
    return isf32 ? ((const float*)p)[i] : bf2f(((const u16*)p)[i]);
}

// L2-executed atomic returning old value (sc0 = return-old). Round-6 finding:
// atomics are the ONLY read path that promptly observes peer-CU writes.
__device__ __forceinline__ unsigned l2_atomic_add(unsigned* p, unsigned v) {
    unsigned old;
    asm volatile("global_atomic_add %0, %1, %2, off sc0\n\t"
                 "s_waitcnt vmcnt(0)"
                 : "=&v"(old) : "v"(p), "v"(v) : "memory");
    return old;
}

// 8 A-fragments (one K-quarter) via sc0 loads (L1 bypass -> XCD L2, where peer
// CUs' write-through stores live). Proven correct for *data* in rounds 4/6/7/9.
__device__ __forceinline__ void load_a_frags(const u16* ap, bf16x8* a) {
    asm volatile(
        "global_load_dwordx4 %0, %8, off sc0\n\t"
        "global_load_dwordx4 %1, %8, off offset:64 sc0\n\t"
        "global_load_dwordx4 %2, %8, off offset:128 sc0\n\t"
        "global_load_dwordx4 %3, %8, off offset:192 sc0\n\t"
        "global_load_dwordx4 %4, %8, off offset:256 sc0\n\t"
        "global_load_dwordx4 %5, %8, off offset:320 sc0\n\t"
        "global_load_dwordx4 %6, %8, off offset:384 sc0\n\t"
        "global_load_dwordx4 %7, %8, off offset:448 sc0\n\t"
        "s_waitcnt vmcnt(0)"
        : "=&v"(a[0]), "=&v"(a[1]), "=&v"(a[2]), "=&v"(a[3]),
          "=&v"(a[4]), "=&v"(a[5]), "=&v"(a[6]), "=&v"(a[7])
        : "v"(ap) : "memory");
}

// Mailbox redesign (this round): per-producer flag WORDS.
// Layout: mboxes[xcd][group][consumer][producer] (u32). Producer `slot`
// publishes by PLAIN-storing value (t+2) into word `slot` of every consumer's
// 128B array (single writer per word -> zero RMW accumulation at the L2 bank,
// unlike the old 32-increments-on-one-word counter). Consumer polls its own
// 128B with one 32-lane atomic_add(.,0) gather + __all(v >= target).
// word value v <=> "h_{v-1} of this group is published" (init publish = 1).

// LDS ~157KB -> exactly 1 WG/CU (required by the per-XCD ticket scheme).
__global__ __launch_bounds__(NT)
void arnn_xcd(const void* __restrict__ xv,
              const void* __restrict__ encwv,
              const void* __restrict__ encbv,
              const void* __restrict__ recwv,
              const void* __restrict__ fgtwv,
              const void* __restrict__ decwv,
              const void* __restrict__ decbv,
              const void* __restrict__ hinitwv,
              const void* __restrict__ hinitbv,
              void* __restrict__ outv,
              u16* __restrict__ h0buf,
              u16* __restrict__ h1buf,
              unsigned* __restrict__ tickets,
              unsigned* __restrict__ mboxes)
{
    // WB: 4 n-tiles of 16 cols in MFMA B-frag lane order (staging only now --
    // all B-fragments are pulled to registers; WB also pins LDS > 80KB so
    // occupancy stays at 1 WG/CU).
    __shared__ short WB[132 * 64 * 8];          // 135168 B
    __shared__ float redC[4 * 5 * 16 * RCP];    // 21760 B: [kq][tile(4=dec)][row][col]
    __shared__ unsigned s_xcd, s_slot;
    __shared__ int s_f32;

    const int tid  = threadIdx.x;
    const int wave = tid >> 6;
    const int lane = tid & 63;
    const int m    = lane & 15;      // C row / A row (batch-local, dup for rows 8..15)
    const int quad = lane >> 4;      // k-subblock within K=32

    // ---- identify XCD, claim per-XCD CU slot ----
    if (tid == 0) {
        unsigned xcc;
        asm volatile("s_getreg_b32 %0, hwreg(HW_REG_XCC_ID, 0, 4)" : "=s"(xcc));
        xcc &= 7u;
        unsigned slot = l2_atomic_add(tickets + xcc * 16, 1u);
        s_xcd = xcc;
        s_slot = slot & 31u;
        s_f32 = 0;
    }
    __syncthreads();
    { // runtime dtype detection on rec_w raw bits (round-1 post-mortem)
        float v = bf2f(((const u16*)recwv)[tid]);
        if (!(v >= -1.0f && v <= 1.0f)) s_f32 = 1;
    }
    __syncthreads();
    const bool isf32 = (s_f32 != 0);
    const int xcd  = (int)s_xcd;
    const int slot = (int)s_slot;
    const int b0   = xcd * (GR * GXR);   // this XCD's batch rows (16)
    const int j0   = slot * CC;          // this CU's hidden cols
    const int dt   = slot & 3;           // dec tile: out cols 16dt..16dt+15
    const bool dec_cu = (slot < 4);      // only these CUs compute/write decode
    unsigned* mbX = mboxes + (size_t)xcd * GR * 32 * MBW;   // this XCD's flag block

    // ---- stage weights into LDS in B-frag order (unchanged) ----
    for (int idx = tid; idx < 132 * 64; idx += NT) {
        int ksg = idx >> 6, l = idx & 63, n = l & 15, q = l >> 4;
        int tile, ksl;
        if (ksg < 34)       { tile = 0; ksl = ksg; }
        else if (ksg < 68)  { tile = 1; ksl = ksg - 34; }
        else if (ksg < 100) { tile = 2; ksl = ksg - 68; }
        else                { tile = 3; ksl = ksg - 100; }
        int j = j0 + ((tile & 1) << 4) + n;
        bf16x8 v;
        if (!isf32) {
            const u16* src;
            if (tile < 2) src = (ksl < 32) ? (const u16*)recwv + (size_t)j * HD + ksl * 32 + q * 8
                                           : (const u16*)encwv + (size_t)j * NI + (ksl - 32) * 32 + q * 8;
            else          src = (const u16*)fgtwv + (size_t)j * HD + ksl * 32 + q * 8;
            v = *(const bf16x8*)src;
        } else {
            const float* src;
            if (tile < 2) src = (ksl < 32) ? (const float*)recwv + (size_t)j * HD + ksl * 32 + q * 8
                                           : (const float*)encwv + (size_t)j * NI + (ksl - 32) * 32 + q * 8;
            else          src = (const float*)fgtwv + (size_t)j * HD + ksl * 32 + q * 8;
            #pragma unroll
            for (int i = 0; i < 8; ++i) v[i] = (short)f2bf(src[i]);
        }
        *(bf16x8*)&WB[idx * 8] = v;
    }
    __syncthreads();     // WB fully staged before register pull

    // ---- ALL B-fragments register-resident (1 wave/SIMD -> ~500 VGPR budget).
    // This removes the per-step LDS B-streaming from the critical path.
    bf16x8 Breg[2][8];   // rec tiles 0,1 for this wave's K-quarter: 64 regs
    bf16x8 Freg[2][8];   // fgt tiles 2,3 for this wave's K-quarter: 64 regs
    #pragma unroll
    for (int ks = 0; ks < 8; ++ks) {
        int kb = wave * 8 + ks;
        Breg[0][ks] = *(const bf16x8*)&WB[((0   + kb) * 64 + lane) * 8];
        Breg[1][ks] = *(const bf16x8*)&WB[((34  + kb) * 64 + lane) * 8];
        Freg[0][ks] = *(const bf16x8*)&WB[((68  + kb) * 64 + lane) * 8];
        Freg[1][ks] = *(const bf16x8*)&WB[((100 + kb) * 64 + lane) * 8];
    }
    bf16x8 Ereg[2];      // enc-tail B-frags (waves 0,1 only): 8 regs
    if (wave < 2) {
        Ereg[0] = *(const bf16x8*)&WB[((32 + wave) * 64 + lane) * 8];
        Ereg[1] = *(const bf16x8*)&WB[((34 + 32 + wave) * 64 + lane) * 8];
    }
    bf16x8 dfr[8];       // dec B-frags for this wave's K-quarter: 32 regs
    {
        int o = 16 * dt + m;         // out column
        #pragma unroll
        for (int ks = 0; ks < 8; ++ks) {
            int kb = wave * 256 + ks * 32 + quad * 8;
            if (!isf32) dfr[ks] = *(const bf16x8*)((const u16*)decwv + (size_t)o * HD + kb);
            else {
                const float* src = (const float*)decwv + (size_t)o * HD + kb;
                #pragma unroll
                for (int i = 0; i < 8; ++i) dfr[ks][i] = (short)f2bf(src[i]);
            }
        }
    }
    // per-thread scalars (XR*CC == NT: exactly one hidden element per thread per group)
    const int er = tid >> 5, ec = tid & 31;                  // (row, col) in 8x32 slice
    float encb_r = ldv(encbv, j0 + ec, isf32);
    float decb_r = ldv(decbv, 16 * dt + (tid & 15), isf32);
    // h0 = hinit_w[:,0] + hinit_b (same for all batch rows); hst in registers
    float h0v = ldv(hinitwv, j0 + ec, isf32) + ldv(hinitbv, j0 + ec, isf32);
    float hst0 = h0v, hst1 = h0v;                            // group 0 / group 1
    h0buf[(size_t)(b0 +       er) * HD + j0 + ec] = f2bf(h0v);
    h0buf[(size_t)(b0 + GXR + er) * HD + j0 + ec] = f2bf(h0v);
    __syncthreads();                             // h0 stores acked by L2 (vmcnt(0))
    if (tid < 32) {                              // publish h_0 for both groups: plain stores
        ((volatile unsigned*)mbX)[0 * 32 * MBW + tid * MBW + slot] = 1u;
        ((volatile unsigned*)mbX)[1 * 32 * MBW + tid * MBW + slot] = 1u;
    }

    // ---- recurrence: two row-groups, out of phase. While group A's
    // publish->poll->load round-trips through L2, group B computes. ----
    for (int t = 0; t < TS; ++t) {
        const u16* cur = (t & 1) ? h1buf : h0buf;
        u16*       nxt = (t & 1) ? h0buf : h1buf;
        #pragma unroll
        for (int g = 0; g < GR; ++g) {
            f32x4 acc[5];
            #pragma unroll
            for (int tt = 0; tt < 5; ++tt) acc[tt] = (f32x4){0.f, 0.f, 0.f, 0.f};

            // enc contribution BEFORE the poll (x is read-only input)
            if (wave < 2) {
                bf16x8 xf;
                size_t xb = (size_t)(b0 + g * GXR + (m & 7)) * (TS * NI) + (size_t)t * NI + wave * 32 + quad * 8;
                if (!isf32) xf = *(const bf16x8*)((const u16*)xv + xb);
                else {
                    const float* xp = (const float*)xv + xb;
                    #pragma unroll
                    for (int i = 0; i < 8; ++i) xf[i] = (short)f2bf(xp[i]);
                }
                acc[0] = __builtin_amdgcn_mfma_f32_16x16x32_bf16(xf, Ereg[0], acc[0], 0, 0, 0);
                acc[1] = __builtin_amdgcn_mfma_f32_16x16x32_bf16(xf, Ereg[1], acc[1], 0, 0, 0);
            }

            // Per-wave poll: 32-lane atomic gather of per-producer words.
            // In steady state the other group's compute phase already covered
            // the publish latency, so this succeeds on iteration 1.
            {
                const unsigned target = (unsigned)(t + 1);
                unsigned* pb = mbX + g * 32 * MBW + slot * MBW;
                for (;;) {
                    unsigned v = 0xFFFFFFFFu;
                    if (lane < 32) v = l2_atomic_add(pb + lane, 0u);
                    if (__all((int)(v >= target))) break;
                }
            }

            bf16x8 a[8];
            load_a_frags(cur + (size_t)(b0 + g * GXR + (m & 7)) * HD + wave * 256 + quad * 8, a);

            #pragma unroll
            for (int ks = 0; ks < 8; ++ks) {
                acc[0] = __builtin_amdgcn_mfma_f32_16x16x32_bf16(a[ks], Breg[0][ks], acc[0], 0, 0, 0);
                acc[1] = __builtin_amdgcn_mfma_f32_16x16x32_bf16(a[ks], Breg[1][ks], acc[1], 0, 0, 0);
                acc[2] = __builtin_amdgcn_mfma_f32_16x16x32_bf16(a[ks], Freg[0][ks], acc[2], 0, 0, 0);
                acc[3] = __builtin_amdgcn_mfma_f32_16x16x32_bf16(a[ks], Freg[1][ks], acc[3], 0, 0, 0);
            }
            if (dec_cu) {   // dec partials only where they are consumed
                #pragma unroll
                for (int ks = 0; ks < 8; ++ks)
                    acc[4] = __builtin_amdgcn_mfma_f32_16x16x32_bf16(a[ks], dfr[ks], acc[4], 0, 0, 0);
            }

            // C-layout 16x16: col = lane&15, row = quad*4 + reg (rows 8..15 dup junk)
            #pragma unroll
            for (int tt = 0; tt < 4; ++tt) {
                #pragma unroll
                for (int r = 0; r < 4; ++r)
                    redC[((wave * 5 + tt) * 16 + quad * 4 + r) * RCP + m] = acc[tt][r];
            }
            if (dec_cu) {
                #pragma unroll
                for (int r = 0; r < 4; ++r)
                    redC[((wave * 5 + 4) * 16 + quad * 4 + r) * RCP + m] = acc[4][r];
            }
            __syncthreads();

            // decode h_t -> out[t-1] for this group's 8 rows (reads complete
            // before the pre-publish barrier; off the h critical path)
            if (dec_cu && t > 0 && tid < 128) {
                int r = tid >> 4, col = tid & 15;
                float o = decb_r;
                #pragma unroll
                for (int kq = 0; kq < 4; ++kq)
                    o += redC[((kq * 5 + 4) * 16 + r) * RCP + col];
                size_t oi = (size_t)(t - 1) * (BS * NO) + (size_t)(b0 + g * GXR + r) * NO + 16 * dt + col;
                if (isf32) ((float*)outv)[oi] = o; else ((u16*)outv)[oi] = f2bf(o);
            }
            // cross-wave K-reduction + elementwise update + h store (1 elem/thread)
            {
                const int tl = ec >> 4, col = ec & 15;
                float pr = encb_r, pf = 0.f;
                #pragma unroll
                for (int kq = 0; kq < 4; ++kq) {
                    pr += redC[((kq * 5 + tl) * 16 + er) * RCP + col];
                    pf += redC[((kq * 5 + 2 + tl) * 16 + er) * RCP + col];
                }
                float fg = 1.0f / (1.0f + __expf(-pf));
                float hn = pr / (1.0f + fabsf(pr));
                float h  = (g == 0) ? hst0 : hst1;
                float hv = h + fg * (hn - h);
                if (g == 0) hst0 = hv; else hst1 = hv;
                nxt[(size_t)(b0 + g * GXR + er) * HD + j0 + ec] = f2bf(hv);
            }
            __syncthreads();       // all waves' h (and out) stores acked by L2
            // publish h_{t+1} of this group: plain single-writer word stores
            if (tid < 32)
                ((volatile unsigned*)mbX)[g * 32 * MBW + tid * MBW + slot] = (unsigned)(t + 2);
        }
    }

    // ---- epilogue: out[511] = decode(h_512) per group; final hidden ----
    #pragma unroll
    for (int g = 0; g < GR; ++g) {
        if (dec_cu) {
            const unsigned target = (unsigned)(TS + 1);
            unsigned* pb = mbX + g * 32 * MBW + slot * MBW;
            for (;;) {
                unsigned v = 0xFFFFFFFFu;
                if (lane < 32) v = l2_atomic_add(pb + lane, 0u);
                if (__all((int)(v >= target))) break;
            }
            bf16x8 a[8];
            load_a_frags(h0buf + (size_t)(b0 + g * GXR + (m & 7)) * HD + wave * 256 + quad * 8, a);
            f32x4 ac = (f32x4){0.f, 0.f, 0.f, 0.f};
            #pragma unroll
            for (int ks = 0; ks < 8; ++ks)
                ac = __builtin_amdgcn_mfma_f32_16x16x32_bf16(a[ks], dfr[ks], ac, 0, 0, 0);
            #pragma unroll
            for (int r = 0; r < 4; ++r)
                redC[((wave * 5 + 4) * 16 + quad * 4 + r) * RCP + m] = ac[r];
        }
        __syncthreads();
        if (dec_cu && tid < 128) {
            int r = tid >> 4, col = tid & 15;
            float o = decb_r;
            #pragma unroll
            for (int kq = 0; kq < 4; ++kq)
                o += redC[((kq * 5 + 4) * 16 + r) * RCP + col];
            size_t oi = (size_t)511 * (BS * NO) + (size_t)(b0 + g * GXR + r) * NO + 16 * dt + col;
            if (isf32) ((float*)outv)[oi] = o; else ((u16*)outv)[oi] = f2bf(o);
        }
        {   // final hidden straight from registers
            size_t oi = (size_t)TS * BS * NO + (size_t)(b0 + g * GXR + er) * HD + j0 + ec;
            float v = (g == 0) ? hst0 : hst1;
            if (isf32) ((float*)outv)[oi] = v; else ((u16*)outv)[oi] = f2bf(v);
        }
        __syncthreads();   // redC reused by next group's epilogue
    }
}

extern "C" void kernel_launch(void* const* d_in, const int* in_sizes, int n_in,
                              void* d_out, int out_size, void* d_ws, size_t ws_size,
                              hipStream_t stream) {
    (void)in_sizes; (void)n_in; (void)out_size; (void)ws_size;
    const void* xv       = d_in[0];
    const void* encwv    = d_in[1];
    const void* encbv    = d_in[2];
    const void* recwv    = d_in[3];
    const void* fgtwv    = d_in[4];
    const void* decwv    = d_in[5];
    const void* decbv    = d_in[6];
    const void* hinitwv  = d_in[7];
    const void* hinitbv  = d_in[8];
    void* outv = d_out;

    unsigned* tickets = (unsigned*)d_ws;                       // 8 x 64B-stride
    unsigned* mboxes  = (unsigned*)((char*)d_ws + 4096);       // 8 XCDs x 2 groups x 32 cons x 128B
    u16* h0buf = (u16*)((char*)d_ws + 524288);
    u16* h1buf = h0buf + (size_t)BS * HD;

    // zero tickets + mailboxes each launch (ws is re-poisoned to 0xAA)
    hipMemsetAsync(d_ws, 0, 4096 + GR * 8 * 32 * MBW * 4, stream);

    void* args[] = { (void*)&xv, (void*)&encwv, (void*)&encbv, (void*)&recwv,
                     (void*)&fgtwv, (void*)&decwv, (void*)&decbv,
                     (void*)&hinitwv, (void*)&hinitbv,
                     (void*)&outv, (void*)&h0buf, (void*)&h1buf,
                     (void*)&tickets, (void*)&mboxes };
    // Round-8 lesson: NEVER ignore the cooperative-launch return code.
    hipError_t err = hipLaunchCooperativeKernel((void*)arnn_xcd, dim3(NWG), dim3(NT), args, 0, stream);
    if (err != hipSuccess) {
        hipLaunchKernelGGL(arnn_xcd, dim3(NWG), dim3(NT), 0, stream,
                           xv, encwv, encbv, recwv, fgtwv, decwv, decbv,
                           hinitwv, hinitbv, outv, h0buf, h1buf, tickets, mboxes);
    }
}

// Round 2
// 1416.763 us; speedup vs baseline: 1.6896x; 1.6896x over previous
//
#include <hip/hip_runtime.h>

typedef unsigned short u16;

#define NWG 256
#define NT  256
#define TS  512
#define HD  1024
#define BS  128
#define NI  64
#define NO  64
#define XR  16      // batch rows per XCD
#define CC  32      // hidden cols per CU
#define RCP 17      // redC padded row stride

typedef __attribute__((ext_vector_type(8))) short bf16x8;
typedef __attribute__((ext_vector_type(4))) float f32x4;

__device__ __forceinline__ float bf2f(u16 u) {
    union { unsigned int i; float f; } v; v.i = ((unsigned int)u) << 16; return v.f;
}
__device__ __forceinline__ u16 f2bf(float f) {
    union { float fl; unsigned int i; } v; v.fl = f;
    unsigned int x = v.i;
    return (u16)((x + 0x7fffu + ((x >> 16) & 1u)) >> 16);  // RNE, finite inputs
}
__device__ __forceinline__ float ldv(const void* p, size_t i, bool isf32) {
    return isf32 ? ((const float*)p)[i] : bf2f(((const u16*)p)[i]);
}

// L2-executed atomic returning old value (sc0 = return-old). Round-6 finding:
// atomics are the ONLY read path that promptly observes peer-CU writes.
__device__ __forceinline__ unsigned l2_atomic_add(unsigned* p, unsigned v) {
    unsigned old;
    asm volatile("global_atomic_add %0, %1, %2, off sc0\n\t"
                 "s_waitcnt vmcnt(0)"
                 : "=&v"(old) : "v"(p), "v"(v) : "memory");
    return old;
}
// Fire-and-forget atomic SWAP (no return): executes in L2 (stays L2-resident,
// unlike round-1's volatile plain stores which wrote through to HBM and made
// every poll an HBM miss). Single-writer-per-word => no RMW accumulation
// (round-0's 32-increments-on-one-word counter serialized ~32 RMWs on the
// release path every step).
__device__ __forceinline__ void l2_atomic_swap_nr(unsigned* p, unsigned v) {
    asm volatile("global_atomic_swap %0, %1, off" :: "v"(p), "v"(v) : "memory");
}

// 8 A-fragments (one K-quarter) via sc0 loads (L1 bypass -> XCD L2, where peer
// CUs' write-through stores live). Proven correct for *data* in rounds 4/6/7/9.
__device__ __forceinline__ void load_a_frags(const u16* ap, bf16x8* a) {
    asm volatile(
        "global_load_dwordx4 %0, %8, off sc0\n\t"
        "global_load_dwordx4 %1, %8, off offset:64 sc0\n\t"
        "global_load_dwordx4 %2, %8, off offset:128 sc0\n\t"
        "global_load_dwordx4 %3, %8, off offset:192 sc0\n\t"
        "global_load_dwordx4 %4, %8, off offset:256 sc0\n\t"
        "global_load_dwordx4 %5, %8, off offset:320 sc0\n\t"
        "global_load_dwordx4 %6, %8, off offset:384 sc0\n\t"
        "global_load_dwordx4 %7, %8, off offset:448 sc0\n\t"
        "s_waitcnt vmcnt(0)"
        : "=&v"(a[0]), "=&v"(a[1]), "=&v"(a[2]), "=&v"(a[3]),
          "=&v"(a[4]), "=&v"(a[5]), "=&v"(a[6]), "=&v"(a[7])
        : "v"(ap) : "memory");
}

// Mailbox layout: mb[xcd][consumer(32)][wave(4)][producer(8)] u32, i.e. each
// (consumer,wave) owns a private 64B line holding the 8 flag words of the
// producers that wave depends on (wave w's K-quarter = producer slots 8w..8w+7).
// Producer slot s publishes h_t by swapping value (t+1) into word
// mb[c][s>>3][s&7] for every consumer c. Consumer wave w polls ONLY its own
// 8 words (one 8-lane atomic gather = one L2 round trip). value v >= t+1 <=>
// h_t published. WAR safety of the h ping-pong is the same induction as the
// old counter scheme: a CU stores h_{t+1} only after ALL its waves (joined at
// the redC barrier) observed h_t from all 32 producers, and producing h_t
// implies that producer finished reading h_{t-1}.
#define MBL 16      // u32 words per (consumer,wave) line (64B)

// LDS ~157KB -> exactly 1 WG/CU (required by the per-XCD ticket scheme).
__global__ __launch_bounds__(NT)
void arnn_xcd(const void* __restrict__ xv,
              const void* __restrict__ encwv,
              const void* __restrict__ encbv,
              const void* __restrict__ recwv,
              const void* __restrict__ fgtwv,
              const void* __restrict__ decwv,
              const void* __restrict__ decbv,
              const void* __restrict__ hinitwv,
              const void* __restrict__ hinitbv,
              void* __restrict__ outv,
              u16* __restrict__ h0buf,
              u16* __restrict__ h1buf,
              unsigned* __restrict__ tickets,
              unsigned* __restrict__ mboxes)
{
    // WB: staging for register fragment pull (also pins LDS -> 1 WG/CU).
    __shared__ short WB[132 * 64 * 8];          // 135168 B
    __shared__ float redC[4 * 5 * 16 * RCP];    // 21760 B: [kq][tile(4=dec)][row][col]
    __shared__ unsigned s_xcd, s_slot;
    __shared__ int s_f32;

    const int tid  = threadIdx.x;
    const int wave = tid >> 6;
    const int lane = tid & 63;
    const int m    = lane & 15;      // C row / A row (batch-local)
    const int quad = lane >> 4;      // k-subblock within K=32

    // ---- identify XCD, claim per-XCD CU slot ----
    if (tid == 0) {
        unsigned xcc;
        asm volatile("s_getreg_b32 %0, hwreg(HW_REG_XCC_ID, 0, 4)" : "=s"(xcc));
        xcc &= 7u;
        unsigned slot = l2_atomic_add(tickets + xcc * 16, 1u);
        s_xcd = xcc;
        s_slot = slot & 31u;
        s_f32 = 0;
    }
    __syncthreads();
    { // runtime dtype detection on rec_w raw bits (round-1 post-mortem)
        float v = bf2f(((const u16*)recwv)[tid]);
        if (!(v >= -1.0f && v <= 1.0f)) s_f32 = 1;
    }
    __syncthreads();
    const bool isf32 = (s_f32 != 0);
    const int xcd  = (int)s_xcd;
    const int slot = (int)s_slot;
    const int b0   = xcd * XR;       // this XCD's batch rows
    const int j0   = slot * CC;      // this CU's hidden cols
    const int dt   = slot & 3;       // dec tile: out cols 16dt..16dt+15
    unsigned* mbX   = mboxes + (size_t)xcd * 32 * 4 * MBL;      // XCD's flag block
    unsigned* mbW   = mbX + (slot * 4 + wave) * MBL;            // this wave's 8 flags
    // producer-side publish target word (per consumer c, computed in loop):
    const int pw = (slot >> 3), pi = (slot & 7);

    // ---- stage weights into LDS in B-frag order ----
    for (int idx = tid; idx < 132 * 64; idx += NT) {
        int ksg = idx >> 6, l = idx & 63, n = l & 15, q = l >> 4;
        int tile, ksl;
        if (ksg < 34)       { tile = 0; ksl = ksg; }
        else if (ksg < 68)  { tile = 1; ksl = ksg - 34; }
        else if (ksg < 100) { tile = 2; ksl = ksg - 68; }
        else                { tile = 3; ksl = ksg - 100; }
        int j = j0 + ((tile & 1) << 4) + n;
        bf16x8 v;
        if (!isf32) {
            const u16* src;
            if (tile < 2) src = (ksl < 32) ? (const u16*)recwv + (size_t)j * HD + ksl * 32 + q * 8
                                           : (const u16*)encwv + (size_t)j * NI + (ksl - 32) * 32 + q * 8;
            else          src = (const u16*)fgtwv + (size_t)j * HD + ksl * 32 + q * 8;
            v = *(const bf16x8*)src;
        } else {
            const float* src;
            if (tile < 2) src = (ksl < 32) ? (const float*)recwv + (size_t)j * HD + ksl * 32 + q * 8
                                           : (const float*)encwv + (size_t)j * NI + (ksl - 32) * 32 + q * 8;
            else          src = (const float*)fgtwv + (size_t)j * HD + ksl * 32 + q * 8;
            #pragma unroll
            for (int i = 0; i < 8; ++i) v[i] = (short)f2bf(src[i]);
        }
        *(bf16x8*)&WB[idx * 8] = v;
    }
    __syncthreads();     // WB fully staged before register pull

    // ---- ALL B-fragments register-resident (1 wave/SIMD -> big VGPR budget).
    bf16x8 Breg[2][8];   // rec tiles 0,1 for this wave's K-quarter
    bf16x8 Freg[2][8];   // fgt tiles 2,3 for this wave's K-quarter
    #pragma unroll
    for (int ks = 0; ks < 8; ++ks) {
        int kb = wave * 8 + ks;
        Breg[0][ks] = *(const bf16x8*)&WB[((0   + kb) * 64 + lane) * 8];
        Breg[1][ks] = *(const bf16x8*)&WB[((34  + kb) * 64 + lane) * 8];
        Freg[0][ks] = *(const bf16x8*)&WB[((68  + kb) * 64 + lane) * 8];
        Freg[1][ks] = *(const bf16x8*)&WB[((100 + kb) * 64 + lane) * 8];
    }
    bf16x8 Ereg[2];      // enc-tail B-frags (waves 0,1 only)
    if (wave < 2) {
        Ereg[0] = *(const bf16x8*)&WB[((32 + wave) * 64 + lane) * 8];
        Ereg[1] = *(const bf16x8*)&WB[((34 + 32 + wave) * 64 + lane) * 8];
    }
    bf16x8 dfr[8];       // dec B-frags for this wave's K-quarter
    {
        int o = 16 * dt + m;         // out column
        #pragma unroll
        for (int ks = 0; ks < 8; ++ks) {
            int kb = wave * 256 + ks * 32 + quad * 8;
            if (!isf32) dfr[ks] = *(const bf16x8*)((const u16*)decwv + (size_t)o * HD + kb);
            else {
                const float* src = (const float*)decwv + (size_t)o * HD + kb;
                #pragma unroll
                for (int i = 0; i < 8; ++i) dfr[ks][i] = (short)f2bf(src[i]);
            }
        }
    }
    // per-thread scalars; h state lives in registers (2 elems/thread: rows er, er+8)
    const int er = tid >> 5, ec = tid & 31;                  // (row, col) of elem 0
    float encb_r = ldv(encbv, j0 + ec, isf32);
    float decb_r = ldv(decbv, 16 * dt + (tid & 15), isf32);
    float h0v = ldv(hinitwv, j0 + ec, isf32) + ldv(hinitbv, j0 + ec, isf32);
    float hstA = h0v, hstB = h0v;                            // rows er / er+8
    h0buf[(size_t)(b0 + er    ) * HD + j0 + ec] = f2bf(h0v);
    h0buf[(size_t)(b0 + er + 8) * HD + j0 + ec] = f2bf(h0v);
    __syncthreads();                             // h0 stores acked by L2 (vmcnt(0))
    if (tid < 32)                                // publish h_0: value 1
        l2_atomic_swap_nr(mbX + (tid * 4 + pw) * MBL + pi, 1u);

    // ---- recurrence ----
    for (int t = 0; t < TS; ++t) {
        f32x4 acc[5];
        #pragma unroll
        for (int tt = 0; tt < 5; ++tt) acc[tt] = (f32x4){0.f, 0.f, 0.f, 0.f};

        // enc contribution BEFORE the wait (x is read-only input)
        if (wave < 2) {
            bf16x8 xf;
            size_t xb = (size_t)(b0 + m) * (TS * NI) + (size_t)t * NI + wave * 32 + quad * 8;
            if (!isf32) xf = *(const bf16x8*)((const u16*)xv + xb);
            else {
                const float* xp = (const float*)xv + xb;
                #pragma unroll
                for (int i = 0; i < 8; ++i) xf[i] = (short)f2bf(xp[i]);
            }
            acc[0] = __builtin_amdgcn_mfma_f32_16x16x32_bf16(xf, Ereg[0], acc[0], 0, 0, 0);
            acc[1] = __builtin_amdgcn_mfma_f32_16x16x32_bf16(xf, Ereg[1], acc[1], 0, 0, 0);
        }

        // Per-wave poll: one 8-lane atomic gather of this wave's OWN producer
        // flags (private 64B line; straggler set is 8 CUs, not 32; no RMW
        // accumulation anywhere).
        {
            const unsigned target = (unsigned)(t + 1);
            for (;;) {
                unsigned v = target;
                if (lane < 8) v = l2_atomic_add(mbW + lane, 0u);
                if (__all((int)(v >= target))) break;
            }
        }

        const u16* cur = (t & 1) ? h1buf : h0buf;
        u16*       nxt = (t & 1) ? h0buf : h1buf;

        bf16x8 a[8];
        load_a_frags(cur + (size_t)(b0 + m) * HD + wave * 256 + quad * 8, a);

        #pragma unroll
        for (int ks = 0; ks < 8; ++ks) {
            acc[0] = __builtin_amdgcn_mfma_f32_16x16x32_bf16(a[ks], Breg[0][ks], acc[0], 0, 0, 0);
            acc[1] = __builtin_amdgcn_mfma_f32_16x16x32_bf16(a[ks], Breg[1][ks], acc[1], 0, 0, 0);
            acc[2] = __builtin_amdgcn_mfma_f32_16x16x32_bf16(a[ks], Freg[0][ks], acc[2], 0, 0, 0);
            acc[3] = __builtin_amdgcn_mfma_f32_16x16x32_bf16(a[ks], Freg[1][ks], acc[3], 0, 0, 0);
            acc[4] = __builtin_amdgcn_mfma_f32_16x16x32_bf16(a[ks], dfr[ks],     acc[4], 0, 0, 0);
        }

        // C-layout 16x16: col = lane&15, row = quad*4 + reg
        #pragma unroll
        for (int tt = 0; tt < 5; ++tt) {
            #pragma unroll
            for (int r = 0; r < 4; ++r)
                redC[((wave * 5 + tt) * 16 + quad * 4 + r) * RCP + m] = acc[tt][r];
        }
        __syncthreads();

        // elementwise FIRST (h stores issue early -> their L2 acks overlap the
        // decode below; the pre-publish barrier then waits less)
        {
            const int tl = ec >> 4, col = ec & 15;
            float pr0 = encb_r, pf0 = 0.f, pr1 = encb_r, pf1 = 0.f;
            #pragma unroll
            for (int kq = 0; kq < 4; ++kq) {
                pr0 += redC[((kq * 5 + tl) * 16 + er) * RCP + col];
                pf0 += redC[((kq * 5 + 2 + tl) * 16 + er) * RCP + col];
                pr1 += redC[((kq * 5 + tl) * 16 + er + 8) * RCP + col];
                pf1 += redC[((kq * 5 + 2 + tl) * 16 + er + 8) * RCP + col];
            }
            float fg0 = 1.0f / (1.0f + __expf(-pf0));
            float hn0 = pr0 / (1.0f + fabsf(pr0));
            hstA = hstA + fg0 * (hn0 - hstA);
            nxt[(size_t)(b0 + er) * HD + j0 + ec] = f2bf(hstA);
            float fg1 = 1.0f / (1.0f + __expf(-pf1));
            float hn1 = pr1 / (1.0f + fabsf(pr1));
            hstB = hstB + fg1 * (hn1 - hstB);
            nxt[(size_t)(b0 + er + 8) * HD + j0 + ec] = f2bf(hstB);
        }
        // decode h_t -> out[t-1]
        if (slot < 4 && t > 0) {
            int r = tid >> 4, col = tid & 15;
            float o = decb_r;
            #pragma unroll
            for (int kq = 0; kq < 4; ++kq)
                o += redC[((kq * 5 + 4) * 16 + r) * RCP + col];
            size_t oi = (size_t)(t - 1) * (BS * NO) + (size_t)(b0 + r) * NO + 16 * dt + col;
            if (isf32) ((float*)outv)[oi] = o; else ((u16*)outv)[oi] = f2bf(o);
        }
        __syncthreads();                       // all waves' h (and out) stores acked by L2
        if (tid < 32)                          // publish h_{t+1}: value t+2
            l2_atomic_swap_nr(mbX + (tid * 4 + pw) * MBL + pi, (unsigned)(t + 2));
    }

    // ---- epilogue: out[511] = decode(h_512); final hidden ----
    if (slot < 4) {
        {   // per-wave poll for h_512 (value TS+1)
            const unsigned target = (unsigned)(TS + 1);
            for (;;) {
                unsigned v = target;
                if (lane < 8) v = l2_atomic_add(mbW + lane, 0u);
                if (__all((int)(v >= target))) break;
            }
        }
        bf16x8 a[8];
        load_a_frags(h0buf + (size_t)(b0 + m) * HD + wave * 256 + quad * 8, a);
        f32x4 ac = (f32x4){0.f, 0.f, 0.f, 0.f};
        #pragma unroll
        for (int ks = 0; ks < 8; ++ks)
            ac = __builtin_amdgcn_mfma_f32_16x16x32_bf16(a[ks], dfr[ks], ac, 0, 0, 0);
        #pragma unroll
        for (int r = 0; r < 4; ++r)
            redC[((wave * 5 + 4) * 16 + quad * 4 + r) * RCP + m] = ac[r];
        __syncthreads();
        {
            int r = tid >> 4, col = tid & 15;
            float o = decb_r;
            #pragma unroll
            for (int kq = 0; kq < 4; ++kq)
                o += redC[((kq * 5 + 4) * 16 + r) * RCP + col];
            size_t oi = (size_t)511 * (BS * NO) + (size_t)(b0 + r) * NO + 16 * dt + col;
            if (isf32) ((float*)outv)[oi] = o; else ((u16*)outv)[oi] = f2bf(o);
        }
    }
    {   // final hidden straight from registers
        size_t oi0 = (size_t)TS * BS * NO + (size_t)(b0 + er) * HD + j0 + ec;
        size_t oi1 = (size_t)TS * BS * NO + (size_t)(b0 + er + 8) * HD + j0 + ec;
        if (isf32) { ((float*)outv)[oi0] = hstA; ((float*)outv)[oi1] = hstB; }
        else       { ((u16*)outv)[oi0] = f2bf(hstA); ((u16*)outv)[oi1] = f2bf(hstB); }
    }
}

extern "C" void kernel_launch(void* const* d_in, const int* in_sizes, int n_in,
                              void* d_out, int out_size, void* d_ws, size_t ws_size,
                              hipStream_t stream) {
    (void)in_sizes; (void)n_in; (void)out_size; (void)ws_size;
    const void* xv       = d_in[0];
    const void* encwv    = d_in[1];
    const void* encbv    = d_in[2];
    const void* recwv    = d_in[3];
    const void* fgtwv    = d_in[4];
    const void* decwv    = d_in[5];
    const void* decbv    = d_in[6];
    const void* hinitwv  = d_in[7];
    const void* hinitbv  = d_in[8];
    void* outv = d_out;

    unsigned* tickets = (unsigned*)d_ws;                       // 8 x 64B-stride
    unsigned* mboxes  = (unsigned*)((char*)d_ws + 4096);       // 8 x 32 x 4 x 64B = 64KB
    u16* h0buf = (u16*)((char*)d_ws + 524288);
    u16* h1buf = h0buf + (size_t)BS * HD;

    // zero tickets + mailboxes each launch (ws is re-poisoned to 0xAA)
    hipMemsetAsync(d_ws, 0, 4096 + 8 * 32 * 4 * MBL * 4, stream);

    void* args[] = { (void*)&xv, (void*)&encwv, (void*)&encbv, (void*)&recwv,
                     (void*)&fgtwv, (void*)&decwv, (void*)&decbv,
                     (void*)&hinitwv, (void*)&hinitbv,
                     (void*)&outv, (void*)&h0buf, (void*)&h1buf,
                     (void*)&tickets, (void*)&mboxes };
    // Round-8 lesson: NEVER ignore the cooperative-launch return code.
    hipError_t err = hipLaunchCooperativeKernel((void*)arnn_xcd, dim3(NWG), dim3(NT), args, 0, stream);
    if (err != hipSuccess) {
        hipLaunchKernelGGL(arnn_xcd, dim3(NWG), dim3(NT), 0, stream,
                           xv, encwv, encbv, recwv, fgtwv, decwv, decbv,
                           hinitwv, hinitbv, outv, h0buf, h1buf, tickets, mboxes);
    }
}